// Round 4
// baseline (281.095 us; speedup 1.0000x reference)
//
#include <hip/hip_runtime.h>

namespace {
constexpr int NB = 256, NN = 1024, DIN = 64, HID = 256, DOUT = 128;
constexpr int MT = 64;               // rows per tile
constexpr int NH = 512;              // rows per half-block

typedef __attribute__((ext_vector_type(8))) short bf16x8;
typedef __attribute__((ext_vector_type(4))) float f32x4;

// ws: w1p [DIN*HID] bf16 (32 KB), w2p [HID*HID] bf16 (128 KB),
//     pool partials [2*NB][HID] f32 (512 KB), counts [2*NB] int, flags [NB] int
constexpr size_t PW1_OFF  = 0;
constexpr size_t PW2_OFF  = (size_t)DIN * HID * 2;
constexpr size_t POOL_OFF = PW2_OFF + (size_t)HID * HID * 2;
constexpr size_t CNT_OFF  = POOL_OFF + (size_t)2 * NB * HID * 4;
constexpr size_t FLAG_OFF = CNT_OFF + (size_t)2 * NB * 4;

__device__ inline unsigned short f2bf(float f) {   // RNE float->bf16
    union { float f; unsigned u; } v; v.f = f;
    unsigned r = v.u + 0x7FFF + ((v.u >> 16) & 1);
    return (unsigned short)(r >> 16);
}

// ---- kernel 0: pack W1/W2 into MFMA frag order; zero per-batch rho flags ----
// lane holds W[k0+(lane>>4)*8+j][n0+(lane&15)], j=0..7 (dual A/B-frag layout).
// w1p shorts: strip*1024 + kk*512 + lane*8 + j   (strip=n>>4, kk=k>>5)
// w2p shorts: strip*4096 + kk*512 + lane*8 + j
__global__ void prep(const float* __restrict__ pw1, const float* __restrict__ pw2,
                     unsigned short* __restrict__ w1p, unsigned short* __restrict__ w2p,
                     int* __restrict__ flag) {
    int i = blockIdx.x * 256 + threadIdx.x;        // 32 blocks x 256 = 8192
    if (blockIdx.x == 0 && threadIdx.x < NB) flag[threadIdx.x] = 0;
    if (i < DIN * HID / 8) {
        int s0 = i * 8;
        int k = s0 >> 8, n0 = s0 & 255;
        float4 v0 = *(const float4*)(pw1 + s0);
        float4 v1 = *(const float4*)(pw1 + s0 + 4);
        float vv[8] = {v0.x, v0.y, v0.z, v0.w, v1.x, v1.y, v1.z, v1.w};
        int j = k & 7, quad = (k >> 3) & 3, kk = k >> 5;
#pragma unroll
        for (int e = 0; e < 8; ++e) {
            int n = n0 + e, strip = n >> 4, l15 = n & 15;
            w1p[strip * 1024 + kk * 512 + (quad * 16 + l15) * 8 + j] = f2bf(vv[e]);
        }
    }
    if (i < HID * HID / 8) {
        int s0 = i * 8;
        int k = s0 >> 8, n0 = s0 & 255;
        float4 v0 = *(const float4*)(pw2 + s0);
        float4 v1 = *(const float4*)(pw2 + s0 + 4);
        float vv[8] = {v0.x, v0.y, v0.z, v0.w, v1.x, v1.y, v1.z, v1.w};
        int j = k & 7, quad = (k >> 3) & 3, kk = k >> 5;
#pragma unroll
        for (int e = 0; e < 8; ++e) {
            int n = n0 + e, strip = n >> 4, l15 = n & 15;
            w2p[strip * 4096 + kk * 512 + (quad * 16 + l15) * 8 + j] = f2bf(vv[e]);
        }
    }
}

// fp32 GEMV segment for the rho chain: 512 thr, c=t&63 (4 cols), s=t>>6 (8 k-segs of 32)
__device__ inline float4 dotseg(const float* __restrict__ buf, const float* __restrict__ W,
                                int c, int s) {
    const float4* W4 = (const float4*)W;           // rows of 64 float4 (N=256)
    float4 acc = make_float4(0.f, 0.f, 0.f, 0.f);
#pragma unroll 8
    for (int i = 0; i < 32; ++i) {
        int k = s * 32 + i;
        float bk = buf[k];
        float4 w = W4[(size_t)k * 64 + c];
        acc.x = fmaf(bk, w.x, acc.x);
        acc.y = fmaf(bk, w.y, acc.y);
        acc.z = fmaf(bk, w.z, acc.z);
        acc.w = fmaf(bk, w.w, acc.w);
    }
    return acc;
}

// ---- phi kernel: 2 blocks per batch (half each); last arriver also runs rho ----
// Swapped MFMA operands: D = mfma(Wfrag, Xfrag) -> lane holds h[row=l15][col=quad*4+r],
// so layer-1 h1s stores are 8B contiguous (ds_write_b64), not 32 scattered b16.
__launch_bounds__(512, 2)   // 2 blocks/CU (CUDA semantics) -> VGPR cap 128
__global__ void phi_full(const float* __restrict__ x, const int* __restrict__ mask,
                         const float* __restrict__ pb1, const float* __restrict__ pb2,
                         const unsigned short* __restrict__ w1p,
                         const unsigned short* __restrict__ w2p,
                         const float* __restrict__ pw3, const float* __restrict__ pb3,
                         const float* __restrict__ rw1, const float* __restrict__ rb1,
                         const float* __restrict__ rw2, const float* __restrict__ rb2,
                         const float* __restrict__ rw3, const float* __restrict__ rb3,
                         float* __restrict__ pool_part, int* __restrict__ cnt_part,
                         int* __restrict__ flag, float* __restrict__ out)
{
    __shared__ unsigned short xs[2][MT * 64];   // 16 KB, XOR-swizzled, double-buffered
    __shared__ unsigned short h1s[MT * 256];    // 32 KB, XOR-swizzled
    __shared__ short vlist[NH];                 // 1 KB
    __shared__ float pooledS[HID];              // 1 KB (rho input)
    __shared__ float part[8][HID];              // 8 KB (rho partials)
    __shared__ float bufB[HID], bufC[HID];      // 2 KB
    __shared__ int cnt_s, rho_s;

    const int bid = blockIdx.x;
    const int b = bid >> 1, half = bid & 1;
    const int t = threadIdx.x;
    const int lane = t & 63, wq = t >> 6;
    const int quad = lane >> 4, l15 = lane & 15;

    // ---- compact valid indices via ballot scan (order irrelevant: sum-pool) ----
    if (t == 0) cnt_s = 0;
    __syncthreads();
    {
        int m = mask[b * NN + half * NH + t] != 0;
        unsigned long long bal = __ballot(m);
        int pos = __popcll(bal & ((1ULL << lane) - 1ULL));
        int wbase = 0;
        if (lane == 0) wbase = atomicAdd(&cnt_s, (int)__popcll(bal));
        wbase = __shfl(wbase, 0, 64);
        if (m) vlist[wbase + pos] = (short)t;
    }
    __syncthreads();
    const int cnt = cnt_s;

    // ---- W fragments -> registers (once per block; inner loop is LDS+MFMA only) ----
    const uint4* w1q = (const uint4*)w1p;
    const uint4* w2q = (const uint4*)w2p;
    uint4 w1f[2][2], w2f[8][2];
#pragma unroll
    for (int j = 0; j < 2; ++j) {
        int strip = wq * 2 + j;
#pragma unroll
        for (int kk = 0; kk < 2; ++kk) w1f[kk][j] = w1q[(strip * 2 + kk) * 64 + lane];
#pragma unroll
        for (int kk = 0; kk < 8; ++kk) w2f[kk][j] = w2q[(strip * 8 + kk) * 64 + lane];
    }

    const float* xb = x + ((size_t)b * NN + (size_t)half * NH) * DIN;
    const int gr = t >> 3, seg8 = t & 7;                 // gather: row, 16B-block
    const int xoff = gr * 64 + ((seg8 ^ (gr & 7)) << 3); // swizzled xs offset (shorts)

    // ---- preload tile 0 ----
    {
        float4 a0 = make_float4(0.f,0.f,0.f,0.f), a1 = a0;
        if (gr < min(MT, cnt)) {
            const float4* p = (const float4*)(xb + (size_t)vlist[gr] * DIN + seg8 * 8);
            a0 = p[0]; a1 = p[1];
        }
        unsigned short tmp[8] = {f2bf(a0.x),f2bf(a0.y),f2bf(a0.z),f2bf(a0.w),
                                 f2bf(a1.x),f2bf(a1.y),f2bf(a1.z),f2bf(a1.w)};
        *(uint4*)&xs[0][xoff] = *(const uint4*)tmp;
    }

    float pool[2][4] = {{0.f,0.f,0.f,0.f},{0.f,0.f,0.f,0.f}};
    const int cb0 = wq * 32 + quad * 4;           // lane's column base (+ j*16)
    const int sw = l15 & 7;                       // row-XOR swizzle key (row = f*16+l15)
    int cur = 0;

    for (int base = 0; base < cnt; base += MT) {
        __syncthreads();                                  // B_top: xs[cur] visible, h1s readers done

        // ---- layer 1: xs -> h1s (K=64), swapped operands ----
        f32x4 acc[2][4];
#pragma unroll
        for (int j = 0; j < 2; ++j)
#pragma unroll
            for (int f = 0; f < 4; ++f) acc[j][f] = (f32x4){0.f,0.f,0.f,0.f};
#pragma unroll
        for (int kk = 0; kk < 2; ++kk) {
            bf16x8 a[4];
#pragma unroll
            for (int f = 0; f < 4; ++f)
                a[f] = *(const bf16x8*)&xs[cur][(f*16 + l15)*64 + (((kk*4 + quad) ^ sw) << 3)];
#pragma unroll
            for (int j = 0; j < 2; ++j) {
                bf16x8 bw = __builtin_bit_cast(bf16x8, w1f[kk][j]);
#pragma unroll
                for (int f = 0; f < 4; ++f)
                    acc[j][f] = __builtin_amdgcn_mfma_f32_16x16x32_bf16(bw, a[f], acc[j][f], 0, 0, 0);
            }
        }

        // lane holds 4 consecutive cols at row f*16+l15 -> pack + b64 store
#pragma unroll
        for (int j = 0; j < 2; ++j) {
            float4 b1 = *(const float4*)&pb1[cb0 + j * 16];
            int kb = wq * 4 + j * 2 + (quad >> 1);
#pragma unroll
            for (int f = 0; f < 4; ++f) {
                int row = f * 16 + l15;
                unsigned lo = (unsigned)f2bf(fmaxf(acc[j][f][0] + b1.x, 0.f))
                            | ((unsigned)f2bf(fmaxf(acc[j][f][1] + b1.y, 0.f)) << 16);
                unsigned hi = (unsigned)f2bf(fmaxf(acc[j][f][2] + b1.z, 0.f))
                            | ((unsigned)f2bf(fmaxf(acc[j][f][3] + b1.w, 0.f)) << 16);
                *(uint2*)&h1s[row * 256 + ((kb ^ sw) << 3) + ((quad & 1) << 2)] = make_uint2(lo, hi);
            }
        }

        // ---- prefetch next x tile into regs (drains at B_mid, covered by L1) ----
        float4 n0 = make_float4(0.f,0.f,0.f,0.f), n1 = n0;
        const bool hn = (base + MT) < cnt;
        if (hn && gr < cnt - (base + MT)) {
            const float4* p = (const float4*)(xb + (size_t)vlist[base + MT + gr] * DIN + seg8 * 8);
            n0 = p[0]; n1 = p[1];
        }
        __syncthreads();                                  // B_mid: h1s visible

        // ---- layer 2: h1s -> pool (K=256), swapped operands, W2 from registers ----
        f32x4 acc2[2][4];
#pragma unroll
        for (int j = 0; j < 2; ++j)
#pragma unroll
            for (int f = 0; f < 4; ++f) acc2[j][f] = (f32x4){0.f,0.f,0.f,0.f};
#pragma unroll
        for (int kk = 0; kk < 8; ++kk) {
            bf16x8 a[4];
#pragma unroll
            for (int f = 0; f < 4; ++f)
                a[f] = *(const bf16x8*)&h1s[(f*16 + l15)*256 + (((kk*4 + quad) ^ sw) << 3)];
#pragma unroll
            for (int j = 0; j < 2; ++j) {
                bf16x8 bw = __builtin_bit_cast(bf16x8, w2f[kk][j]);
#pragma unroll
                for (int f = 0; f < 4; ++f)
                    acc2[j][f] = __builtin_amdgcn_mfma_f32_16x16x32_bf16(bw, a[f], acc2[j][f], 0, 0, 0);
            }
        }

        // validity is per (f,l15) row — uniform over j,r
#pragma unroll
        for (int j = 0; j < 2; ++j) {
            float4 b2 = *(const float4*)&pb2[cb0 + j * 16];
#pragma unroll
            for (int f = 0; f < 4; ++f) {
                bool vf = (base + f * 16 + l15) < cnt;
                float h0 = fmaxf(acc2[j][f][0] + b2.x, 0.f);
                float h1 = fmaxf(acc2[j][f][1] + b2.y, 0.f);
                float h2 = fmaxf(acc2[j][f][2] + b2.z, 0.f);
                float h3 = fmaxf(acc2[j][f][3] + b2.w, 0.f);
                pool[j][0] += vf ? h0 : 0.f;
                pool[j][1] += vf ? h1 : 0.f;
                pool[j][2] += vf ? h2 : 0.f;
                pool[j][3] += vf ? h3 : 0.f;
            }
        }

        if (hn) {
            unsigned short tmp[8] = {f2bf(n0.x),f2bf(n0.y),f2bf(n0.z),f2bf(n0.w),
                                     f2bf(n1.x),f2bf(n1.y),f2bf(n1.z),f2bf(n1.w)};
            *(uint4*)&xs[cur ^ 1][xoff] = *(const uint4*)tmp;
        }
        cur ^= 1;
    }

    // ---- pool reduce over the 16 row-lanes (l15); cols are lane-disjoint per quad ----
#pragma unroll
    for (int j = 0; j < 2; ++j)
#pragma unroll
        for (int r = 0; r < 4; ++r) {
            float v = pool[j][r];
            v += __shfl_xor(v, 1, 64);
            v += __shfl_xor(v, 2, 64);
            v += __shfl_xor(v, 4, 64);
            v += __shfl_xor(v, 8, 64);
            pool[j][r] = v;
        }
    if (l15 == 0) {
#pragma unroll
        for (int j = 0; j < 2; ++j) {
            float4 pv = make_float4(pool[j][0], pool[j][1], pool[j][2], pool[j][3]);
            *(float4*)&pool_part[(size_t)bid * HID + cb0 + j * 16] = pv;
        }
    }
    if (t == 0) cnt_part[bid] = cnt;

    // ---- last-arriver handshake: second block of this batch runs rho ----
    __threadfence();                              // release our partial+cnt (per-thread)
    __syncthreads();                              // ALL threads' stores fenced before ticket
    if (t == 0) rho_s = (atomicAdd(&flag[b], 1) == 1);
    __syncthreads();
    if (!rho_s) return;
    __threadfence();                              // acquire partner's partial+cnt

    if (t < HID)
        pooledS[t] = pool_part[(size_t)(2 * b) * HID + t]
                   + pool_part[(size_t)(2 * b + 1) * HID + t];
    if (t == 0) cnt_s = cnt_part[2 * b] + cnt_part[2 * b + 1];
    __syncthreads();
    const int ctot = cnt_s;

    // ---- fused rho (fp32): folded pw3 + 3-layer chain ----
    const int c = t & 63, s = t >> 6;
    {
        float4 p = dotseg(pooledS, pw3, c, s);
        ((float4*)part[s])[c] = p;
        __syncthreads();
        if (t < HID) {
            float v = (float)ctot * pb3[t];
#pragma unroll
            for (int g = 0; g < 8; ++g) v += part[g][t];
            bufB[t] = v;
        }
        __syncthreads();
    }
    {
        float4 p = dotseg(bufB, rw1, c, s);
        ((float4*)part[s])[c] = p;
        __syncthreads();
        if (t < HID) {
            float v = rb1[t];
#pragma unroll
            for (int g = 0; g < 8; ++g) v += part[g][t];
            bufC[t] = fmaxf(v, 0.f);
        }
        __syncthreads();
    }
    {
        float4 p = dotseg(bufC, rw2, c, s);
        ((float4*)part[s])[c] = p;
        __syncthreads();
        if (t < HID) {
            float v = rb2[t];
#pragma unroll
            for (int g = 0; g < 8; ++g) v += part[g][t];
            bufB[t] = fmaxf(v, 0.f);
        }
        __syncthreads();
    }
    {   // final layer, N=128: c4=t&31 (4 cols), s4=t>>5 (16 k-segs of 16)
        const int c4 = t & 31, s4 = t >> 5;
        const float4* W4 = (const float4*)rw3;
        float4 acc = make_float4(0.f, 0.f, 0.f, 0.f);
#pragma unroll 8
        for (int i = 0; i < 16; ++i) {
            int k = s4 * 16 + i;
            float bk = bufB[k];
            float4 w = W4[(size_t)k * 32 + c4];
            acc.x = fmaf(bk, w.x, acc.x);
            acc.y = fmaf(bk, w.y, acc.y);
            acc.z = fmaf(bk, w.z, acc.z);
            acc.w = fmaf(bk, w.w, acc.w);
        }
        float* part2 = &part[0][0];               // reuse as [16][128]
        ((float4*)(part2 + s4 * DOUT))[c4] = acc;
        __syncthreads();
        if (t < DOUT) {
            float v = rb3[t];
#pragma unroll
            for (int g = 0; g < 16; ++g) v += part2[g * DOUT + t];
            out[b * DOUT + t] = (ctot > 0) ? v : 0.f;
        }
    }
}
} // namespace

extern "C" void kernel_launch(void* const* d_in, const int* in_sizes, int n_in,
                              void* d_out, int out_size, void* d_ws, size_t ws_size,
                              hipStream_t stream) {
    const float* x    = (const float*)d_in[0];
    const int*   mask = (const int*)  d_in[1];
    const float* pw1  = (const float*)d_in[2];
    const float* pb1  = (const float*)d_in[3];
    const float* pw2  = (const float*)d_in[4];
    const float* pb2  = (const float*)d_in[5];
    const float* pw3  = (const float*)d_in[6];
    const float* pb3  = (const float*)d_in[7];
    const float* rw1  = (const float*)d_in[8];
    const float* rb1  = (const float*)d_in[9];
    const float* rw2  = (const float*)d_in[10];
    const float* rb2  = (const float*)d_in[11];
    const float* rw3  = (const float*)d_in[12];
    const float* rb3  = (const float*)d_in[13];
    float* out = (float*)d_out;

    unsigned short* w1p = (unsigned short*)((char*)d_ws + PW1_OFF);
    unsigned short* w2p = (unsigned short*)((char*)d_ws + PW2_OFF);
    float* pool_part = (float*)((char*)d_ws + POOL_OFF);
    int* cnt_part = (int*)((char*)d_ws + CNT_OFF);
    int* flag = (int*)((char*)d_ws + FLAG_OFF);

    prep<<<dim3(32), dim3(256), 0, stream>>>(pw1, pw2, w1p, w2p, flag);
    phi_full<<<dim3(NB * 2), dim3(512), 0, stream>>>(x, mask, pb1, pb2, w1p, w2p,
                                                     pw3, pb3, rw1, rb1, rw2, rb2, rw3, rb3,
                                                     pool_part, cnt_part, flag, out);
}

// Round 5
// 227.777 us; speedup vs baseline: 1.2341x; 1.2341x over previous
//
#include <hip/hip_runtime.h>

namespace {
constexpr int NB = 256, NN = 1024, DIN = 64, HID = 256, DOUT = 128;
constexpr int MT = 64;               // rows per tile
constexpr int NH2 = 512;             // rows per half-pipeline

typedef __attribute__((ext_vector_type(8))) short bf16x8;
typedef __attribute__((ext_vector_type(4))) float f32x4;

// ws: w1p [DIN*HID] bf16 (32 KB), w2p [HID*HID] bf16 (128 KB)
constexpr size_t PW1_OFF  = 0;
constexpr size_t PW2_OFF  = (size_t)DIN * HID * 2;

__device__ inline unsigned short f2bf(float f) {   // RNE float->bf16
    union { float f; unsigned u; } v; v.f = f;
    unsigned r = v.u + 0x7FFF + ((v.u >> 16) & 1);
    return (unsigned short)(r >> 16);
}

// ---- kernel 0: pack W1/W2 into MFMA B-frag order (round-0/3 version) ----
// B-frag (16x16x32): lane holds W[k0+(lane>>4)*8+j][n0+(lane&15)], j=0..7.
// w1p shorts: strip*1024 + kk*512 + lane*8 + j   (strip=n>>4, kk=k>>5)
// w2p shorts: strip*4096 + kk*512 + lane*8 + j
__global__ void prep(const float* __restrict__ pw1, const float* __restrict__ pw2,
                     unsigned short* __restrict__ w1p, unsigned short* __restrict__ w2p) {
    int i = blockIdx.x * 256 + threadIdx.x;        // 32 blocks x 256 = 8192
    if (i < DIN * HID / 8) {
        int s0 = i * 8;
        int k = s0 >> 8, n0 = s0 & 255;
        float4 v0 = *(const float4*)(pw1 + s0);
        float4 v1 = *(const float4*)(pw1 + s0 + 4);
        float vv[8] = {v0.x, v0.y, v0.z, v0.w, v1.x, v1.y, v1.z, v1.w};
        int j = k & 7, quad = (k >> 3) & 3, kk = k >> 5;
#pragma unroll
        for (int e = 0; e < 8; ++e) {
            int n = n0 + e, strip = n >> 4, l15 = n & 15;
            w1p[strip * 1024 + kk * 512 + (quad * 16 + l15) * 8 + j] = f2bf(vv[e]);
        }
    }
    if (i < HID * HID / 8) {
        int s0 = i * 8;
        int k = s0 >> 8, n0 = s0 & 255;
        float4 v0 = *(const float4*)(pw2 + s0);
        float4 v1 = *(const float4*)(pw2 + s0 + 4);
        float vv[8] = {v0.x, v0.y, v0.z, v0.w, v1.x, v1.y, v1.z, v1.w};
        int j = k & 7, quad = (k >> 3) & 3, kk = k >> 5;
#pragma unroll
        for (int e = 0; e < 8; ++e) {
            int n = n0 + e, strip = n >> 4, l15 = n & 15;
            w2p[strip * 4096 + kk * 512 + (quad * 16 + l15) * 8 + j] = f2bf(vv[e]);
        }
    }
}

// fp32 GEMV segment, 1024 threads: c=t&63 (4 cols of 64 float4), s=t>>6 (16 k-segs of 16)
__device__ inline float4 dotseg16(const float* __restrict__ buf, const float* __restrict__ W,
                                  int c, int s) {
    const float4* W4 = (const float4*)W;           // rows of 64 float4 (N=256)
    float4 acc = make_float4(0.f, 0.f, 0.f, 0.f);
#pragma unroll 8
    for (int i = 0; i < 16; ++i) {
        int k = s * 16 + i;
        float bk = buf[k];
        float4 w = W4[(size_t)k * 64 + c];
        acc.x = fmaf(bk, w.x, acc.x);
        acc.y = fmaf(bk, w.y, acc.y);
        acc.z = fmaf(bk, w.z, acc.z);
        acc.w = fmaf(bk, w.w, acc.w);
    }
    return acc;
}

// ---- fused kernel: 1 block (1024 thr) per batch = two 512-thr half-pipelines + in-block rho.
// No cross-block communication (round-2/4 lesson: agent-scope fences cost ~140us on gfx950).
__launch_bounds__(1024, 1)   // 16 waves/CU resident -> VGPR cap 128
__global__ void deepset_fused(const float* __restrict__ x, const int* __restrict__ mask,
                              const float* __restrict__ pb1, const float* __restrict__ pb2,
                              const unsigned short* __restrict__ w1p,
                              const unsigned short* __restrict__ w2p,
                              const float* __restrict__ pw3, const float* __restrict__ pb3,
                              const float* __restrict__ rw1, const float* __restrict__ rb1,
                              const float* __restrict__ rw2, const float* __restrict__ rb2,
                              const float* __restrict__ rw3, const float* __restrict__ rb3,
                              float* __restrict__ out)
{
    __shared__ unsigned short xs[2][2][MT * 64];  // [half][dbuf] 32 KB, XOR-swizzled
    __shared__ unsigned short h1s[2][MT * 256];   // 64 KB, XOR-swizzled
    __shared__ short vlist[2][NH2];               // 2 KB
    __shared__ float poolH[2][HID];               // 2 KB
    __shared__ float part[16][HID];               // 16 KB (reused as [32][128] in last layer)
    __shared__ float bufB[HID], bufC[HID];        // 2 KB
    __shared__ int cnt_sh[2];

    const int b = blockIdx.x;
    const int t = threadIdx.x;
    const int hh = t >> 9, u = t & 511;           // half id, thread-in-half
    const int lane = u & 63, wq = u >> 6;         // wave lane, wave-in-half (0..7)
    const int quad = lane >> 4, l15 = lane & 15;

    // ---- compact valid indices per half via ballot scan (order irrelevant: sum-pool) ----
    if (t < 2) cnt_sh[t] = 0;
    __syncthreads();
    {
        int m = mask[b * NN + hh * NH2 + u] != 0;
        unsigned long long bal = __ballot(m);     // wave lies entirely within one half
        int pos = __popcll(bal & ((1ULL << lane) - 1ULL));
        int wbase = 0;
        if (lane == 0) wbase = atomicAdd(&cnt_sh[hh], (int)__popcll(bal));
        wbase = __shfl(wbase, 0, 64);
        if (m) vlist[hh][wbase + pos] = (short)u;
    }
    __syncthreads();
    const int cnt = cnt_sh[hh];                        // own half's count
    const int mx = max(cnt_sh[0], cnt_sh[1]);          // unified trip count (barrier safety)

    // ---- W fragments -> registers (identical for both halves) ----
    const uint4* w1q = (const uint4*)w1p;
    const uint4* w2q = (const uint4*)w2p;
    uint4 w1f[2][2], w2f[8][2];
#pragma unroll
    for (int j = 0; j < 2; ++j) {
        int strip = wq * 2 + j;
#pragma unroll
        for (int kk = 0; kk < 2; ++kk) w1f[kk][j] = w1q[(strip * 2 + kk) * 64 + lane];
#pragma unroll
        for (int kk = 0; kk < 8; ++kk) w2f[kk][j] = w2q[(strip * 8 + kk) * 64 + lane];
    }
    float bias1[2], bias2[2];
#pragma unroll
    for (int j = 0; j < 2; ++j) {
        int c = wq * 32 + j * 16 + l15;
        bias1[j] = pb1[c]; bias2[j] = pb2[c];
    }

    float pool[2] = {0.f, 0.f};
    const float* xb = x + ((size_t)b * NN + (size_t)hh * NH2) * DIN;
    const int gr = u >> 3, seg8 = u & 7;                 // gather: row, 16B-block
    const int xoff = gr * 64 + ((seg8 ^ (gr & 7)) << 3); // swizzled xs offset (shorts)

    // ---- preload tile 0 ----
    {
        float4 a0 = make_float4(0.f,0.f,0.f,0.f), a1 = a0;
        if (gr < min(MT, cnt)) {
            const float4* p = (const float4*)(xb + (size_t)vlist[hh][gr] * DIN + seg8 * 8);
            a0 = p[0]; a1 = p[1];
        }
        unsigned short tmp[8] = {f2bf(a0.x),f2bf(a0.y),f2bf(a0.z),f2bf(a0.w),
                                 f2bf(a1.x),f2bf(a1.y),f2bf(a1.z),f2bf(a1.w)};
        *(uint4*)&xs[hh][0][xoff] = *(const uint4*)tmp;
    }

    int cur = 0;
    for (int base = 0; base < mx; base += MT) {
        __syncthreads();                                  // B_top: xs[cur] visible, h1s readers done

        // ---- layer 1: xs -> h1s (K=64) ----
        f32x4 acc[4][2];
#pragma unroll
        for (int f = 0; f < 4; ++f)
#pragma unroll
            for (int j = 0; j < 2; ++j) acc[f][j] = (f32x4){0.f,0.f,0.f,0.f};
#pragma unroll
        for (int kk = 0; kk < 2; ++kk) {
            bf16x8 a[4];
#pragma unroll
            for (int f = 0; f < 4; ++f)
                a[f] = *(const bf16x8*)&xs[hh][cur][(f*16 + l15)*64 + (((kk*4 + quad) ^ (l15 & 7)) << 3)];
#pragma unroll
            for (int j = 0; j < 2; ++j) {
                bf16x8 bw = __builtin_bit_cast(bf16x8, w1f[kk][j]);
#pragma unroll
                for (int f = 0; f < 4; ++f)
                    acc[f][j] = __builtin_amdgcn_mfma_f32_16x16x32_bf16(a[f], bw, acc[f][j], 0, 0, 0);
            }
        }
#pragma unroll
        for (int f = 0; f < 4; ++f)
#pragma unroll
            for (int j = 0; j < 2; ++j) {
                int col = wq * 32 + j * 16 + l15, kb = col >> 3, cl = col & 7;
#pragma unroll
                for (int r = 0; r < 4; ++r) {
                    int row = f * 16 + quad * 4 + r;
                    float h = fmaxf(acc[f][j][r] + bias1[j], 0.f);
                    h1s[hh][row * 256 + ((kb ^ (row & 7)) << 3) + cl] = f2bf(h);
                }
            }

        // ---- prefetch next x tile into regs (drains at B_mid) ----
        float4 n0 = make_float4(0.f,0.f,0.f,0.f), n1 = n0;
        const bool hstore = (base + MT) < mx;             // store decision: unified bound
        if (gr < cnt - (base + MT)) {                     // load guard: own count
            const float4* p = (const float4*)(xb + (size_t)vlist[hh][base + MT + gr] * DIN + seg8 * 8);
            n0 = p[0]; n1 = p[1];
        }
        __syncthreads();                                  // B_mid: h1s visible

        // ---- layer 2: h1s -> pool (K=256), W2 from registers ----
        f32x4 acc2[4][2];
#pragma unroll
        for (int f = 0; f < 4; ++f)
#pragma unroll
            for (int j = 0; j < 2; ++j) acc2[f][j] = (f32x4){0.f,0.f,0.f,0.f};
#pragma unroll
        for (int kk = 0; kk < 8; ++kk) {
            bf16x8 a[4];
#pragma unroll
            for (int f = 0; f < 4; ++f)
                a[f] = *(const bf16x8*)&h1s[hh][(f*16 + l15)*256 + (((kk*4 + quad) ^ (l15 & 7)) << 3)];
#pragma unroll
            for (int j = 0; j < 2; ++j) {
                bf16x8 bw = __builtin_bit_cast(bf16x8, w2f[kk][j]);
#pragma unroll
                for (int f = 0; f < 4; ++f)
                    acc2[f][j] = __builtin_amdgcn_mfma_f32_16x16x32_bf16(a[f], bw, acc2[f][j], 0, 0, 0);
            }
        }
#pragma unroll
        for (int f = 0; f < 4; ++f)
#pragma unroll
            for (int r = 0; r < 4; ++r) {
                bool v = (base + f * 16 + quad * 4 + r) < cnt;
#pragma unroll
                for (int j = 0; j < 2; ++j) {
                    float h = fmaxf(acc2[f][j][r] + bias2[j], 0.f);
                    pool[j] += v ? h : 0.f;
                }
            }

        if (hstore) {
            unsigned short tmp[8] = {f2bf(n0.x),f2bf(n0.y),f2bf(n0.z),f2bf(n0.w),
                                     f2bf(n1.x),f2bf(n1.y),f2bf(n1.z),f2bf(n1.w)};
            *(uint4*)&xs[hh][cur ^ 1][xoff] = *(const uint4*)tmp;
        }
        cur ^= 1;
    }

    // ---- pool reduce per half: cross-quad shuffle, cols wave-disjoint ----
#pragma unroll
    for (int j = 0; j < 2; ++j) {
        float v = pool[j];
        v += __shfl_xor(v, 16, 64);
        v += __shfl_xor(v, 32, 64);
        if (quad == 0) poolH[hh][wq * 32 + j * 16 + l15] = v;
    }
    __syncthreads();

    // ---- combine halves -> pooled vector in bufC ----
    const int ctot = cnt_sh[0] + cnt_sh[1];
    if (t < HID) bufC[t] = poolH[0][t] + poolH[1][t];
    __syncthreads();

    // ---- fused rho (fp32, 1024 threads): folded pw3 + 3-layer chain ----
    const int c = t & 63, s = t >> 6;                 // 4 cols, 16 k-segs of 16
    {
        float4 p = dotseg16(bufC, pw3, c, s);
        ((float4*)part[s])[c] = p;
        __syncthreads();
        if (t < HID) {
            float v = (float)ctot * pb3[t];
#pragma unroll
            for (int g = 0; g < 16; ++g) v += part[g][t];
            bufB[t] = v;
        }
        __syncthreads();
    }
    {
        float4 p = dotseg16(bufB, rw1, c, s);
        ((float4*)part[s])[c] = p;
        __syncthreads();
        if (t < HID) {
            float v = rb1[t];
#pragma unroll
            for (int g = 0; g < 16; ++g) v += part[g][t];
            bufC[t] = fmaxf(v, 0.f);
        }
        __syncthreads();
    }
    {
        float4 p = dotseg16(bufC, rw2, c, s);
        ((float4*)part[s])[c] = p;
        __syncthreads();
        if (t < HID) {
            float v = rb2[t];
#pragma unroll
            for (int g = 0; g < 16; ++g) v += part[g][t];
            bufB[t] = fmaxf(v, 0.f);
        }
        __syncthreads();
    }
    {   // final layer, N=128: c4=t&31 (4 cols), s4=t>>5 (32 k-segs of 8)
        const int c4 = t & 31, s4 = t >> 5;
        const float4* W4 = (const float4*)rw3;
        float4 acc = make_float4(0.f, 0.f, 0.f, 0.f);
#pragma unroll 8
        for (int i = 0; i < 8; ++i) {
            int k = s4 * 8 + i;
            float bk = bufB[k];
            float4 w = W4[(size_t)k * 32 + c4];
            acc.x = fmaf(bk, w.x, acc.x);
            acc.y = fmaf(bk, w.y, acc.y);
            acc.z = fmaf(bk, w.z, acc.z);
            acc.w = fmaf(bk, w.w, acc.w);
        }
        float* part2 = &part[0][0];               // reuse as [32][128]
        ((float4*)(part2 + s4 * DOUT))[c4] = acc;
        __syncthreads();
        if (t < DOUT) {
            float v = rb3[t];
#pragma unroll
            for (int g = 0; g < 32; ++g) v += part2[g * DOUT + t];
            out[b * DOUT + t] = (ctot > 0) ? v : 0.f;
        }
    }
}
} // namespace

extern "C" void kernel_launch(void* const* d_in, const int* in_sizes, int n_in,
                              void* d_out, int out_size, void* d_ws, size_t ws_size,
                              hipStream_t stream) {
    const float* x    = (const float*)d_in[0];
    const int*   mask = (const int*)  d_in[1];
    const float* pw1  = (const float*)d_in[2];
    const float* pb1  = (const float*)d_in[3];
    const float* pw2  = (const float*)d_in[4];
    const float* pb2  = (const float*)d_in[5];
    const float* pw3  = (const float*)d_in[6];
    const float* pb3  = (const float*)d_in[7];
    const float* rw1  = (const float*)d_in[8];
    const float* rb1  = (const float*)d_in[9];
    const float* rw2  = (const float*)d_in[10];
    const float* rb2  = (const float*)d_in[11];
    const float* rw3  = (const float*)d_in[12];
    const float* rb3  = (const float*)d_in[13];
    float* out = (float*)d_out;

    unsigned short* w1p = (unsigned short*)((char*)d_ws + PW1_OFF);
    unsigned short* w2p = (unsigned short*)((char*)d_ws + PW2_OFF);

    prep<<<dim3(32), dim3(256), 0, stream>>>(pw1, pw2, w1p, w2p);
    deepset_fused<<<dim3(NB), dim3(1024), 0, stream>>>(x, mask, pb1, pb2, w1p, w2p,
                                                       pw3, pb3, rw1, rb1, rw2, rb2, rw3, rb3,
                                                       out);
}

// Round 6
// 147.731 us; speedup vs baseline: 1.9027x; 1.5418x over previous
//
#include <hip/hip_runtime.h>

namespace {
constexpr int NB = 256, NN = 1024, DIN = 64, HID = 256, DOUT = 128;
constexpr int MT = 64;               // rows per tile

typedef __attribute__((ext_vector_type(8))) short bf16x8;
typedef __attribute__((ext_vector_type(4))) float f32x4;

__device__ inline unsigned short f2bf(float f) {   // RNE float->bf16
    union { float f; unsigned u; } v; v.f = f;
    unsigned r = v.u + 0x7FFF + ((v.u >> 16) & 1);
    return (unsigned short)(r >> 16);
}

// fp32 GEMV segment for the rho chain: 512 thr, c=t&63 (4 cols), s=t>>6 (8 k-segs of 32)
__device__ inline float4 dotseg(const float* __restrict__ buf, const float* __restrict__ W,
                                int c, int s) {
    const float4* W4 = (const float4*)W;           // rows of 64 float4 (N=256)
    float4 acc = make_float4(0.f, 0.f, 0.f, 0.f);
#pragma unroll 8
    for (int i = 0; i < 32; ++i) {
        int k = s * 32 + i;
        float bk = buf[k];
        float4 w = W4[(size_t)k * 64 + c];
        acc.x = fmaf(bk, w.x, acc.x);
        acc.y = fmaf(bk, w.y, acc.y);
        acc.z = fmaf(bk, w.z, acc.z);
        acc.w = fmaf(bk, w.w, acc.w);
    }
    return acc;
}

// ---- single fused kernel: 1 block (512 thr) per batch ----
// In-block W-frag packing (replaces prep dispatch), h1s double-buffered so the
// K-loop runs ONE barrier per tile-window: L1(tile i) + L2(tile i-1) together.
// __launch_bounds__(512,1): VGPR cap 256 (empirical: (512,2)->128, (512,4)/(1024,*)->64
// which spills w2f). Grid 256 = 1 block/CU, 8 waves resident regardless of VGPR<=256.
__launch_bounds__(512, 1)
__global__ void deepset(const float* __restrict__ x, const int* __restrict__ mask,
                        const float* __restrict__ pw1, const float* __restrict__ pb1,
                        const float* __restrict__ pw2, const float* __restrict__ pb2,
                        const float* __restrict__ pw3, const float* __restrict__ pb3,
                        const float* __restrict__ rw1, const float* __restrict__ rb1,
                        const float* __restrict__ rw2, const float* __restrict__ rb2,
                        const float* __restrict__ rw3, const float* __restrict__ rb3,
                        float* __restrict__ out)
{
    __shared__ unsigned short xs[2][MT * 64];   // 16 KB, XOR-swizzled, double-buffered
    __shared__ unsigned short h1s[2][MT * 256]; // 64 KB, XOR-swizzled, double-buffered
    __shared__ short vlist[NN];                 // 2 KB
    __shared__ float pooledS[HID];              // 1 KB
    __shared__ float part[8][HID];              // 8 KB
    __shared__ float bufB[HID], bufC[HID];      // 2 KB
    __shared__ int cnt_s;

    const int b = blockIdx.x, t = threadIdx.x;
    const int lane = t & 63, wq = t >> 6;
    const int quad = lane >> 4, l15 = lane & 15;

    // ---- compact valid indices via ballot scan (order irrelevant: sum-pool) ----
    if (t == 0) cnt_s = 0;
    __syncthreads();
#pragma unroll
    for (int h = 0; h < 2; ++h) {
        int idx = h * 512 + t;
        int m = mask[b * NN + idx] != 0;
        unsigned long long bal = __ballot(m);
        int pos = __popcll(bal & ((1ULL << lane) - 1ULL));
        int wbase = 0;
        if (lane == 0) wbase = atomicAdd(&cnt_s, (int)__popcll(bal));
        wbase = __shfl(wbase, 0, 64);
        if (m) vlist[wbase + pos] = (short)idx;
    }

    // ---- pack W fragments from GLOBAL fp32 (replaces prep kernel; L3-resident) ----
    // frag (kk,j): lane holds W[kk*32 + quad*8 + jj][wq*32 + j*16 + l15], jj=0..7
    uint4 w1f[2][2], w2f[8][2];
    float bias1[2], bias2[2];
#pragma unroll
    for (int j = 0; j < 2; ++j) {
        const int col = wq * 32 + j * 16 + l15;
        bias1[j] = pb1[col]; bias2[j] = pb2[col];
#pragma unroll
        for (int kk = 0; kk < 2; ++kk) {
            unsigned short tmp[8];
#pragma unroll
            for (int jj = 0; jj < 8; ++jj)
                tmp[jj] = f2bf(pw1[(size_t)(kk * 32 + quad * 8 + jj) * HID + col]);
            w1f[kk][j] = *(const uint4*)tmp;
        }
#pragma unroll
        for (int kk = 0; kk < 8; ++kk) {
            unsigned short tmp[8];
#pragma unroll
            for (int jj = 0; jj < 8; ++jj)
                tmp[jj] = f2bf(pw2[(size_t)(kk * 32 + quad * 8 + jj) * HID + col]);
            w2f[kk][j] = *(const uint4*)tmp;
        }
    }

    __syncthreads();
    const int cnt = cnt_s;
    const int T = (cnt + MT - 1) / MT;          // tiles (uniform across block)

    float pool[2] = {0.f, 0.f};
    const float* xb = x + (size_t)b * NN * DIN;
    const int gr = t >> 3, seg8 = t & 7;                 // gather: row, 16B-block
    const int xoff = gr * 64 + ((seg8 ^ (gr & 7)) << 3); // swizzled xs offset (shorts)

    // ---- preload tile 0 ----
    if (T > 0) {
        float4 a0 = make_float4(0.f,0.f,0.f,0.f), a1 = a0;
        if (gr < min(MT, cnt)) {
            const float4* p = (const float4*)(xb + (size_t)vlist[gr] * DIN + seg8 * 8);
            a0 = p[0]; a1 = p[1];
        }
        unsigned short tmp[8] = {f2bf(a0.x),f2bf(a0.y),f2bf(a0.z),f2bf(a0.w),
                                 f2bf(a1.x),f2bf(a1.y),f2bf(a1.z),f2bf(a1.w)};
        *(uint4*)&xs[0][xoff] = *(const uint4*)tmp;
    }

    // ---- pipelined K-loop: window i does L1(tile i) + L2(tile i-1), ONE barrier ----
    int p = 0;
    for (int i = 0; i <= T; ++i, p ^= 1) {
        __syncthreads();   // xs[p] (tile i) and h1s[p^1] (tile i-1) visible; readers of h1s[p], xs[p^1] done
        const bool doL1 = (i < T);
        const bool hn = ((i + 1) * MT) < cnt;   // next tile exists

        // -- prefetch tile i+1 into regs (issued early; drains at xs store below) --
        float4 n0 = make_float4(0.f,0.f,0.f,0.f), n1 = n0;
        if (doL1 && gr < cnt - (i + 1) * MT) {
            const float4* pp = (const float4*)(xb + (size_t)vlist[(i + 1) * MT + gr] * DIN + seg8 * 8);
            n0 = pp[0]; n1 = pp[1];
        }

        // -- layer 1: xs[p] -> h1s[p] (K=64) --
        if (doL1) {
            f32x4 acc[4][2];
#pragma unroll
            for (int f = 0; f < 4; ++f)
#pragma unroll
                for (int j = 0; j < 2; ++j) acc[f][j] = (f32x4){0.f,0.f,0.f,0.f};
#pragma unroll
            for (int kk = 0; kk < 2; ++kk) {
                bf16x8 a[4];
#pragma unroll
                for (int f = 0; f < 4; ++f)
                    a[f] = *(const bf16x8*)&xs[p][(f*16 + l15)*64 + (((kk*4 + quad) ^ (l15 & 7)) << 3)];
#pragma unroll
                for (int j = 0; j < 2; ++j) {
                    bf16x8 bw = __builtin_bit_cast(bf16x8, w1f[kk][j]);
#pragma unroll
                    for (int f = 0; f < 4; ++f)
                        acc[f][j] = __builtin_amdgcn_mfma_f32_16x16x32_bf16(a[f], bw, acc[f][j], 0, 0, 0);
                }
            }
#pragma unroll
            for (int f = 0; f < 4; ++f)
#pragma unroll
                for (int j = 0; j < 2; ++j) {
                    int col = wq * 32 + j * 16 + l15, kb = col >> 3, cl = col & 7;
#pragma unroll
                    for (int r = 0; r < 4; ++r) {
                        int row = f * 16 + quad * 4 + r;
                        float h = fmaxf(acc[f][j][r] + bias1[j], 0.f);
                        h1s[p][row * 256 + ((kb ^ (row & 7)) << 3) + cl] = f2bf(h);
                    }
                }
        }

        // -- layer 2 on PREVIOUS tile: h1s[p^1] -> pool (K=256) --
        if (i > 0) {
            const int basep = (i - 1) * MT;
            f32x4 acc2[4][2];
#pragma unroll
            for (int f = 0; f < 4; ++f)
#pragma unroll
                for (int j = 0; j < 2; ++j) acc2[f][j] = (f32x4){0.f,0.f,0.f,0.f};
#pragma unroll
            for (int kk = 0; kk < 8; ++kk) {
                bf16x8 a[4];
#pragma unroll
                for (int f = 0; f < 4; ++f)
                    a[f] = *(const bf16x8*)&h1s[p ^ 1][(f*16 + l15)*256 + (((kk*4 + quad) ^ (l15 & 7)) << 3)];
#pragma unroll
                for (int j = 0; j < 2; ++j) {
                    bf16x8 bw = __builtin_bit_cast(bf16x8, w2f[kk][j]);
#pragma unroll
                    for (int f = 0; f < 4; ++f)
                        acc2[f][j] = __builtin_amdgcn_mfma_f32_16x16x32_bf16(a[f], bw, acc2[f][j], 0, 0, 0);
                }
            }
#pragma unroll
            for (int f = 0; f < 4; ++f)
#pragma unroll
                for (int r = 0; r < 4; ++r) {
                    bool v = (basep + f * 16 + quad * 4 + r) < cnt;
#pragma unroll
                    for (int j = 0; j < 2; ++j) {
                        float h = fmaxf(acc2[f][j][r] + bias2[j], 0.f);
                        pool[j] += v ? h : 0.f;
                    }
                }
        }

        // -- stage prefetched tile i+1 into xs[p^1] --
        if (hn) {
            unsigned short tmp[8] = {f2bf(n0.x),f2bf(n0.y),f2bf(n0.z),f2bf(n0.w),
                                     f2bf(n1.x),f2bf(n1.y),f2bf(n1.z),f2bf(n1.w)};
            *(uint4*)&xs[p ^ 1][xoff] = *(const uint4*)tmp;
        }
    }

    // ---- pool reduce: cross-quad shuffle, cols are wave-disjoint ----
#pragma unroll
    for (int j = 0; j < 2; ++j) {
        float v = pool[j];
        v += __shfl_xor(v, 16, 64);
        v += __shfl_xor(v, 32, 64);
        if (quad == 0) pooledS[wq * 32 + j * 16 + l15] = v;
    }
    __syncthreads();

    // ---- fused rho (fp32): folded pw3 + 3-layer chain (round-0 verbatim) ----
    const int c = t & 63, s = t >> 6;
    {
        float4 pt = dotseg(pooledS, pw3, c, s);
        ((float4*)part[s])[c] = pt;
        __syncthreads();
        if (t < HID) {
            float v = (float)cnt * pb3[t];
#pragma unroll
            for (int g = 0; g < 8; ++g) v += part[g][t];
            bufB[t] = v;
        }
        __syncthreads();
    }
    {
        float4 pt = dotseg(bufB, rw1, c, s);
        ((float4*)part[s])[c] = pt;
        __syncthreads();
        if (t < HID) {
            float v = rb1[t];
#pragma unroll
            for (int g = 0; g < 8; ++g) v += part[g][t];
            bufC[t] = fmaxf(v, 0.f);
        }
        __syncthreads();
    }
    {
        float4 pt = dotseg(bufC, rw2, c, s);
        ((float4*)part[s])[c] = pt;
        __syncthreads();
        if (t < HID) {
            float v = rb2[t];
#pragma unroll
            for (int g = 0; g < 8; ++g) v += part[g][t];
            bufB[t] = fmaxf(v, 0.f);
        }
        __syncthreads();
    }
    {   // final layer, N=128: c4=t&31 (4 cols), s4=t>>5 (16 k-segs of 16)
        const int c4 = t & 31, s4 = t >> 5;
        const float4* W4 = (const float4*)rw3;
        float4 acc = make_float4(0.f, 0.f, 0.f, 0.f);
#pragma unroll 8
        for (int i = 0; i < 16; ++i) {
            int k = s4 * 16 + i;
            float bk = bufB[k];
            float4 w = W4[(size_t)k * 32 + c4];
            acc.x = fmaf(bk, w.x, acc.x);
            acc.y = fmaf(bk, w.y, acc.y);
            acc.z = fmaf(bk, w.z, acc.z);
            acc.w = fmaf(bk, w.w, acc.w);
        }
        float* part2 = &part[0][0];               // reuse as [16][128]
        ((float4*)(part2 + s4 * DOUT))[c4] = acc;
        __syncthreads();
        if (t < DOUT) {
            float v = rb3[t];
#pragma unroll
            for (int g = 0; g < 16; ++g) v += part2[g * DOUT + t];
            out[b * DOUT + t] = (cnt > 0) ? v : 0.f;
        }
    }
}
} // namespace

extern "C" void kernel_launch(void* const* d_in, const int* in_sizes, int n_in,
                              void* d_out, int out_size, void* d_ws, size_t ws_size,
                              hipStream_t stream) {
    const float* x    = (const float*)d_in[0];
    const int*   mask = (const int*)  d_in[1];
    const float* pw1  = (const float*)d_in[2];
    const float* pb1  = (const float*)d_in[3];
    const float* pw2  = (const float*)d_in[4];
    const float* pb2  = (const float*)d_in[5];
    const float* pw3  = (const float*)d_in[6];
    const float* pb3  = (const float*)d_in[7];
    const float* rw1  = (const float*)d_in[8];
    const float* rb1  = (const float*)d_in[9];
    const float* rw2  = (const float*)d_in[10];
    const float* rb2  = (const float*)d_in[11];
    const float* rw3  = (const float*)d_in[12];
    const float* rb3  = (const float*)d_in[13];
    float* out = (float*)d_out;
    (void)d_ws; (void)ws_size;   // workspace unused: prep folded in-kernel

    deepset<<<dim3(NB), dim3(512), 0, stream>>>(x, mask, pw1, pb1, pw2, pb2,
                                                pw3, pb3, rw1, rb1, rw2, rb2, rw3, rb3, out);
}

// Round 7
// 146.292 us; speedup vs baseline: 1.9215x; 1.0098x over previous
//
#include <hip/hip_runtime.h>

namespace {
constexpr int NB = 256, NN = 1024, DIN = 64, HID = 256, DOUT = 128;
constexpr int MT = 64;               // rows per tile

typedef __attribute__((ext_vector_type(8))) short bf16x8;
typedef __attribute__((ext_vector_type(4))) float f32x4;

__device__ inline unsigned short f2bf(float f) {   // RNE float->bf16
    union { float f; unsigned u; } v; v.f = f;
    unsigned r = v.u + 0x7FFF + ((v.u >> 16) & 1);
    return (unsigned short)(r >> 16);
}

// fp32 GEMV segment for the rho chain: 512 thr, c=t&63 (4 cols), s=t>>6 (8 k-segs of 32)
__device__ inline float4 dotseg(const float* __restrict__ buf, const float* __restrict__ W,
                                int c, int s) {
    const float4* W4 = (const float4*)W;           // rows of 64 float4 (N=256)
    float4 acc = make_float4(0.f, 0.f, 0.f, 0.f);
#pragma unroll 8
    for (int i = 0; i < 32; ++i) {
        int k = s * 32 + i;
        float bk = buf[k];
        float4 w = W4[(size_t)k * 64 + c];
        acc.x = fmaf(bk, w.x, acc.x);
        acc.y = fmaf(bk, w.y, acc.y);
        acc.z = fmaf(bk, w.z, acc.z);
        acc.w = fmaf(bk, w.w, acc.w);
    }
    return acc;
}

// ---- single fused kernel: 1 block (512 thr) per batch ----
// Window i runs L1(tile i) and L2(tile i-1) FUSED in one kk-loop (16 indep
// accumulator chains -> ds_read latency of one stream hides under the other's
// MFMAs). Swapped MFMA operands (D = mfma(Wfrag, Xfrag), R4-verified): lane
// holds 4 consecutive cols -> h1s pack is 8 x ds_write_b64, not 32 x b16.
// __launch_bounds__(512,1): VGPR cap 256 (empirical: (512,2)->128, (512,4)->64).
__launch_bounds__(512, 1)
__global__ void deepset(const float* __restrict__ x, const int* __restrict__ mask,
                        const float* __restrict__ pw1, const float* __restrict__ pb1,
                        const float* __restrict__ pw2, const float* __restrict__ pb2,
                        const float* __restrict__ pw3, const float* __restrict__ pb3,
                        const float* __restrict__ rw1, const float* __restrict__ rb1,
                        const float* __restrict__ rw2, const float* __restrict__ rb2,
                        const float* __restrict__ rw3, const float* __restrict__ rb3,
                        float* __restrict__ out)
{
    __shared__ unsigned short xs[2][MT * 64];   // 16 KB, XOR-swizzled, double-buffered
    __shared__ unsigned short h1s[2][MT * 256]; // 64 KB, XOR-swizzled, double-buffered
    __shared__ short vlist[NN];                 // 2 KB
    __shared__ float pooledS[HID];              // 1 KB
    __shared__ float part[8][HID];              // 8 KB
    __shared__ float bufB[HID], bufC[HID];      // 2 KB
    __shared__ int cnt_s;

    const int b = blockIdx.x, t = threadIdx.x;
    const int lane = t & 63, wq = t >> 6;
    const int quad = lane >> 4, l15 = lane & 15;
    const int sw = l15 & 7;                      // row-XOR swizzle key
    const int cb0 = wq * 32 + quad * 4;          // lane's column base (+ j*16)

    // ---- compact valid indices via ballot scan (order irrelevant: sum-pool) ----
    if (t == 0) cnt_s = 0;
    __syncthreads();
#pragma unroll
    for (int h = 0; h < 2; ++h) {
        int idx = h * 512 + t;
        int m = mask[b * NN + idx] != 0;
        unsigned long long bal = __ballot(m);
        int pos = __popcll(bal & ((1ULL << lane) - 1ULL));
        int wbase = 0;
        if (lane == 0) wbase = atomicAdd(&cnt_s, (int)__popcll(bal));
        wbase = __shfl(wbase, 0, 64);
        if (m) vlist[wbase + pos] = (short)idx;
    }

    // ---- pack W fragments from GLOBAL fp32 (L3-resident; replaces prep) ----
    // frag (kk,j): lane holds W[kk*32 + quad*8 + jj][wq*32 + j*16 + l15], jj=0..7
    uint4 w1f[2][2], w2f[8][2];
    float4 bias1v[2], bias2v[2];
#pragma unroll
    for (int j = 0; j < 2; ++j) {
        const int col = wq * 32 + j * 16 + l15;
        bias1v[j] = *(const float4*)&pb1[cb0 + j * 16];
        bias2v[j] = *(const float4*)&pb2[cb0 + j * 16];
#pragma unroll
        for (int kk = 0; kk < 2; ++kk) {
            unsigned short tmp[8];
#pragma unroll
            for (int jj = 0; jj < 8; ++jj)
                tmp[jj] = f2bf(pw1[(size_t)(kk * 32 + quad * 8 + jj) * HID + col]);
            w1f[kk][j] = *(const uint4*)tmp;
        }
#pragma unroll
        for (int kk = 0; kk < 8; ++kk) {
            unsigned short tmp[8];
#pragma unroll
            for (int jj = 0; jj < 8; ++jj)
                tmp[jj] = f2bf(pw2[(size_t)(kk * 32 + quad * 8 + jj) * HID + col]);
            w2f[kk][j] = *(const uint4*)tmp;
        }
    }

    __syncthreads();
    const int cnt = cnt_s;
    const int T = (cnt + MT - 1) / MT;          // tiles (uniform across block)

    float pool[2][4] = {{0.f,0.f,0.f,0.f},{0.f,0.f,0.f,0.f}};
    const float* xb = x + (size_t)b * NN * DIN;
    const int gr = t >> 3, seg8 = t & 7;                 // gather: row, 16B-block
    const int xoff = gr * 64 + ((seg8 ^ (gr & 7)) << 3); // swizzled xs offset (shorts)

    // ---- preload tile 0 ----
    if (T > 0) {
        float4 a0 = make_float4(0.f,0.f,0.f,0.f), a1 = a0;
        if (gr < min(MT, cnt)) {
            const float4* p = (const float4*)(xb + (size_t)vlist[gr] * DIN + seg8 * 8);
            a0 = p[0]; a1 = p[1];
        }
        unsigned short tmp[8] = {f2bf(a0.x),f2bf(a0.y),f2bf(a0.z),f2bf(a0.w),
                                 f2bf(a1.x),f2bf(a1.y),f2bf(a1.z),f2bf(a1.w)};
        *(uint4*)&xs[0][xoff] = *(const uint4*)tmp;
    }

    // ---- pipelined K-loop: ONE barrier per window; L1(i) and L2(i-1) fused ----
    int p = 0;
    for (int i = 0; i <= T; ++i, p ^= 1) {
        __syncthreads();   // xs[p] (tile i), h1s[p^1] (tile i-1) visible; prior readers done
        const bool doL1 = (i < T);
        const bool doL2 = (i > 0);
        const bool hn = ((i + 1) * MT) < cnt;   // next tile exists

        // -- prefetch tile i+1 into regs (drains at xs store below) --
        float4 n0 = make_float4(0.f,0.f,0.f,0.f), n1 = n0;
        if (doL1 && gr < cnt - (i + 1) * MT) {
            const float4* pp = (const float4*)(xb + (size_t)vlist[(i + 1) * MT + gr] * DIN + seg8 * 8);
            n0 = pp[0]; n1 = pp[1];
        }

        f32x4 acc[2][4], acc2[2][4];
#pragma unroll
        for (int j = 0; j < 2; ++j)
#pragma unroll
            for (int f = 0; f < 4; ++f) {
                acc[j][f]  = (f32x4){0.f,0.f,0.f,0.f};
                acc2[j][f] = (f32x4){0.f,0.f,0.f,0.f};
            }

        // -- fused kk loop: L2 stream (kk 0..7) + L1 stream (kk 0..1), independent chains --
#pragma unroll
        for (int kk = 0; kk < 8; ++kk) {
            bf16x8 aL2[4], aL1[4];
            if (doL2) {
#pragma unroll
                for (int f = 0; f < 4; ++f)
                    aL2[f] = *(const bf16x8*)&h1s[p ^ 1][(f*16 + l15)*256 + (((kk*4 + quad) ^ sw) << 3)];
            }
            if (doL1 && kk < 2) {
#pragma unroll
                for (int f = 0; f < 4; ++f)
                    aL1[f] = *(const bf16x8*)&xs[p][(f*16 + l15)*64 + (((kk*4 + quad) ^ sw) << 3)];
#pragma unroll
                for (int j = 0; j < 2; ++j) {
                    bf16x8 bw = __builtin_bit_cast(bf16x8, w1f[kk][j]);
#pragma unroll
                    for (int f = 0; f < 4; ++f)
                        acc[j][f] = __builtin_amdgcn_mfma_f32_16x16x32_bf16(bw, aL1[f], acc[j][f], 0, 0, 0);
                }
            }
            if (doL2) {
#pragma unroll
                for (int j = 0; j < 2; ++j) {
                    bf16x8 bw2 = __builtin_bit_cast(bf16x8, w2f[kk][j]);
#pragma unroll
                    for (int f = 0; f < 4; ++f)
                        acc2[j][f] = __builtin_amdgcn_mfma_f32_16x16x32_bf16(bw2, aL2[f], acc2[j][f], 0, 0, 0);
                }
            }
        }

        // -- L1 epilogue: lane holds 4 consecutive cols at row f*16+l15 -> b64 stores --
        if (doL1) {
#pragma unroll
            for (int j = 0; j < 2; ++j) {
                int kb = wq * 4 + j * 2 + (quad >> 1);
#pragma unroll
                for (int f = 0; f < 4; ++f) {
                    int row = f * 16 + l15;
                    unsigned lo = (unsigned)f2bf(fmaxf(acc[j][f][0] + bias1v[j].x, 0.f))
                                | ((unsigned)f2bf(fmaxf(acc[j][f][1] + bias1v[j].y, 0.f)) << 16);
                    unsigned hi = (unsigned)f2bf(fmaxf(acc[j][f][2] + bias1v[j].z, 0.f))
                                | ((unsigned)f2bf(fmaxf(acc[j][f][3] + bias1v[j].w, 0.f)) << 16);
                    *(uint2*)&h1s[p][row * 256 + ((kb ^ sw) << 3) + ((quad & 1) << 2)] = make_uint2(lo, hi);
                }
            }
        }

        // -- L2 epilogue: accumulate pool; validity per (f,l15) row --
        if (doL2) {
            const int basep = (i - 1) * MT;
#pragma unroll
            for (int j = 0; j < 2; ++j)
#pragma unroll
                for (int f = 0; f < 4; ++f) {
                    bool vf = (basep + f * 16 + l15) < cnt;
                    float h0 = fmaxf(acc2[j][f][0] + bias2v[j].x, 0.f);
                    float h1 = fmaxf(acc2[j][f][1] + bias2v[j].y, 0.f);
                    float h2 = fmaxf(acc2[j][f][2] + bias2v[j].z, 0.f);
                    float h3 = fmaxf(acc2[j][f][3] + bias2v[j].w, 0.f);
                    pool[j][0] += vf ? h0 : 0.f;
                    pool[j][1] += vf ? h1 : 0.f;
                    pool[j][2] += vf ? h2 : 0.f;
                    pool[j][3] += vf ? h3 : 0.f;
                }
        }

        // -- stage prefetched tile i+1 into xs[p^1] --
        if (hn) {
            unsigned short tmp[8] = {f2bf(n0.x),f2bf(n0.y),f2bf(n0.z),f2bf(n0.w),
                                     f2bf(n1.x),f2bf(n1.y),f2bf(n1.z),f2bf(n1.w)};
            *(uint4*)&xs[p ^ 1][xoff] = *(const uint4*)tmp;
        }
    }

    // ---- pool reduce over the 16 row-lanes (l15); cols lane-disjoint per quad ----
#pragma unroll
    for (int j = 0; j < 2; ++j)
#pragma unroll
        for (int r = 0; r < 4; ++r) {
            float v = pool[j][r];
            v += __shfl_xor(v, 1, 64);
            v += __shfl_xor(v, 2, 64);
            v += __shfl_xor(v, 4, 64);
            v += __shfl_xor(v, 8, 64);
            pool[j][r] = v;
        }
    if (l15 == 0) {
#pragma unroll
        for (int j = 0; j < 2; ++j) {
            float4 pv = make_float4(pool[j][0], pool[j][1], pool[j][2], pool[j][3]);
            *(float4*)&pooledS[cb0 + j * 16] = pv;
        }
    }
    __syncthreads();

    // ---- fused rho (fp32): folded pw3 + 3-layer chain ----
    const int c = t & 63, s = t >> 6;
    {
        float4 pt = dotseg(pooledS, pw3, c, s);
        ((float4*)part[s])[c] = pt;
        __syncthreads();
        if (t < HID) {
            float v = (float)cnt * pb3[t];
#pragma unroll
            for (int g = 0; g < 8; ++g) v += part[g][t];
            bufB[t] = v;
        }
        __syncthreads();
    }
    {
        float4 pt = dotseg(bufB, rw1, c, s);
        ((float4*)part[s])[c] = pt;
        __syncthreads();
        if (t < HID) {
            float v = rb1[t];
#pragma unroll
            for (int g = 0; g < 8; ++g) v += part[g][t];
            bufC[t] = fmaxf(v, 0.f);
        }
        __syncthreads();
    }
    {
        float4 pt = dotseg(bufC, rw2, c, s);
        ((float4*)part[s])[c] = pt;
        __syncthreads();
        if (t < HID) {
            float v = rb2[t];
#pragma unroll
            for (int g = 0; g < 8; ++g) v += part[g][t];
            bufB[t] = fmaxf(v, 0.f);
        }
        __syncthreads();
    }
    {   // final layer, N=128: c4=t&31 (4 cols), s4=t>>5 (16 k-segs of 16)
        const int c4 = t & 31, s4 = t >> 5;
        const float4* W4 = (const float4*)rw3;
        float4 acc = make_float4(0.f, 0.f, 0.f, 0.f);
#pragma unroll 8
        for (int i = 0; i < 16; ++i) {
            int k = s4 * 16 + i;
            float bk = bufB[k];
            float4 w = W4[(size_t)k * 32 + c4];
            acc.x = fmaf(bk, w.x, acc.x);
            acc.y = fmaf(bk, w.y, acc.y);
            acc.z = fmaf(bk, w.z, acc.z);
            acc.w = fmaf(bk, w.w, acc.w);
        }
        float* part2 = &part[0][0];               // reuse as [16][128]
        ((float4*)(part2 + s4 * DOUT))[c4] = acc;
        __syncthreads();
        if (t < DOUT) {
            float v = rb3[t];
#pragma unroll
            for (int g = 0; g < 16; ++g) v += part2[g * DOUT + t];
            out[b * DOUT + t] = (cnt > 0) ? v : 0.f;
        }
    }
}
} // namespace

extern "C" void kernel_launch(void* const* d_in, const int* in_sizes, int n_in,
                              void* d_out, int out_size, void* d_ws, size_t ws_size,
                              hipStream_t stream) {
    const float* x    = (const float*)d_in[0];
    const int*   mask = (const int*)  d_in[1];
    const float* pw1  = (const float*)d_in[2];
    const float* pb1  = (const float*)d_in[3];
    const float* pw2  = (const float*)d_in[4];
    const float* pb2  = (const float*)d_in[5];
    const float* pw3  = (const float*)d_in[6];
    const float* pb3  = (const float*)d_in[7];
    const float* rw1  = (const float*)d_in[8];
    const float* rb1  = (const float*)d_in[9];
    const float* rw2  = (const float*)d_in[10];
    const float* rb2  = (const float*)d_in[11];
    const float* rw3  = (const float*)d_in[12];
    const float* rb3  = (const float*)d_in[13];
    float* out = (float*)d_out;
    (void)d_ws; (void)ws_size;   // workspace unused: prep folded in-kernel

    deepset<<<dim3(NB), dim3(512), 0, stream>>>(x, mask, pw1, pb1, pw2, pb2,
                                                pw3, pb3, rw1, rb1, rw2, rb2, rw3, rb3, out);
}